// Round 1
// baseline (28.490 us; speedup 1.0000x reference)
//
#include <hip/hip_runtime.h>

#define H 200
#define NP 64
#define NIMG 24
#define G 10          // row strips per image
#define ROWS 20       // H / G
#define GSTEP (2.0f/199.0f)

// Kernel 1: per (image, row-strip) block.
//  - compute projected points, per-point sigma
//  - build ex[n][x] (full), ey strip [y][n], Sy[n] (full-y sums), colsum_inv[x]
//  - mask strip = sum_n ey*ex, clamp<=1, write unnormalized to d_out
//  - per-strip mask sum -> ws_msum (deterministic tree reduce)
//  - score partials: T[n,x] = sum_{y in strip} ey*M; fold with ex*cinv -> ws_score
__global__ __launch_bounds__(256) void prs_main(
    const float* __restrict__ cam,   // (8,3,2,3)
    const float* __restrict__ cloud, // (8,64,3)
    const float* __restrict__ mt,    // (8,3,200,200)
    const float* __restrict__ blur,  // (8,64)
    const float* __restrict__ b3,    // (8,3)
    const float* __restrict__ b2,    // (8,3,2)
    float* __restrict__ out,
    float* __restrict__ ws_msum,     // [NIMG*G]
    float* __restrict__ ws_score)    // [NIMG*G][64]
{
  __shared__ float ex[NP * H];       // [n][x]
  __shared__ float eys[ROWS * NP];   // [y][n]  (strip rows only)
  __shared__ float Sy[NP];
  __shared__ float Syp[4 * NP];
  __shared__ float cinv[H];
  __shared__ float ptx[NP], pty[NP], i2s[NP];
  __shared__ float red[256];

  const int tid = threadIdx.x;
  const int blk = blockIdx.x;
  const int img = blk / G;
  const int strip = blk - img * G;
  const int b = img / 3;
  const int c = img - b * 3;
  const int ys0 = strip * ROWS;

  // --- point params ---
  if (tid < NP) {
    int n = tid;
    float p0 = cloud[(b*NP + n)*3 + 0] + b3[b*3 + 0];
    float p1 = cloud[(b*NP + n)*3 + 1] + b3[b*3 + 1];
    float p2 = cloud[(b*NP + n)*3 + 2] + b3[b*3 + 2];
    const float* cc = cam + ((b*3 + c)*2)*3;
    float px = cc[0]*p0 + cc[1]*p1 + cc[2]*p2 - b2[(b*3 + c)*2 + 0];
    float py = cc[3]*p0 + cc[4]*p1 + cc[5]*p2 - b2[(b*3 + c)*2 + 1];
    ptx[n] = fminf(fmaxf(px * 0.01f, -1.0f), 1.0f);
    pty[n] = fminf(fmaxf(py * 0.01f, -1.0f), 1.0f);
    float s = blur[b*NP + n];
    i2s[n] = 1.0f / (2.0f * s * s);
  }
  __syncthreads();

  // --- fill ex table: thread -> (n = tid>>2, 50 x's) ---
  {
    int n  = tid >> 2;
    int x0 = (tid & 3) * 50;
    float pxv = ptx[n], iv = i2s[n];
    for (int x = x0; x < x0 + 50; ++x) {
      float dx = (-1.0f + x * GSTEP) - pxv;
      ex[n*H + x] = __expf(-dx*dx*iv);
    }
  }
  // --- Sy partials (full-y) + strip ey ---
  {
    int n = tid & 63;
    int g = tid >> 6;
    float pyv = pty[n], iv = i2s[n];
    float s = 0.0f;
    for (int y = g*50; y < g*50 + 50; ++y) {
      float dy = (-1.0f + y * GSTEP) - pyv;
      s += __expf(-dy*dy*iv);
    }
    Syp[g*NP + n] = s;
    for (int k = 0; k < 5; ++k) {
      int y = g*5 + k;
      float dy = (-1.0f + (ys0 + y) * GSTEP) - pyv;
      eys[y*NP + n] = __expf(-dy*dy*iv);
    }
  }
  __syncthreads();
  if (tid < NP) Sy[tid] = Syp[tid] + Syp[NP + tid] + Syp[2*NP + tid] + Syp[3*NP + tid];
  __syncthreads();
  if (tid < H) {
    float s = 0.0f;
    for (int n = 0; n < NP; ++n) s += ex[n*H + tid] * Sy[n];
    cinv[tid] = 1.0f / fmaxf(s, 1e-8f);
  }
  __syncthreads();

  // --- mask strip: 4x4 register tiles, 250 tiles ---
  float msl = 0.0f;
  if (tid < 250) {
    int yg = tid / 50;
    int xg = tid - yg * 50;
    int x0 = xg * 4;
    int y0 = yg * 4;
    float acc[4][4];
    #pragma unroll
    for (int i = 0; i < 4; ++i)
      #pragma unroll
      for (int j = 0; j < 4; ++j) acc[i][j] = 0.0f;
    for (int n = 0; n < NP; ++n) {
      float4 exv = *(float4*)&ex[n*H + x0];
      #pragma unroll
      for (int i = 0; i < 4; ++i) {
        float e = eys[(y0 + i)*NP + n];
        acc[i][0] += e * exv.x;
        acc[i][1] += e * exv.y;
        acc[i][2] += e * exv.z;
        acc[i][3] += e * exv.w;
      }
    }
    #pragma unroll
    for (int i = 0; i < 4; ++i) {
      float4 v;
      v.x = fminf(acc[i][0], 1.0f);
      v.y = fminf(acc[i][1], 1.0f);
      v.z = fminf(acc[i][2], 1.0f);
      v.w = fminf(acc[i][3], 1.0f);
      msl += v.x + v.y + v.z + v.w;
      *(float4*)&out[img*(H*H) + (ys0 + y0 + i)*H + x0] = v;
    }
  }
  red[tid] = msl;
  __syncthreads();
  #pragma unroll
  for (int s = 128; s > 0; s >>= 1) {
    if (tid < s) red[tid] += red[tid + s];
    __syncthreads();
  }
  if (tid == 0) ws_msum[blk] = red[0];

  // --- score partials: T[n,x] over strip rows, fold with ex*cinv ---
  {
    int ng = tid >> 4;     // n-group 0..15
    int xt = tid & 15;
    int n0 = ng * 4;
    float sacc[4] = {0.0f, 0.0f, 0.0f, 0.0f};
    for (int xq = xt; xq < 50; xq += 16) {
      int x0 = xq * 4;
      float t[4][4];
      #pragma unroll
      for (int i = 0; i < 4; ++i)
        #pragma unroll
        for (int j = 0; j < 4; ++j) t[i][j] = 0.0f;
      for (int y = 0; y < ROWS; ++y) {
        float4 eyv = *(float4*)&eys[y*NP + n0];
        float4 mv  = *(const float4*)&mt[img*(H*H) + (ys0 + y)*H + x0];
        t[0][0] += eyv.x * mv.x; t[0][1] += eyv.x * mv.y; t[0][2] += eyv.x * mv.z; t[0][3] += eyv.x * mv.w;
        t[1][0] += eyv.y * mv.x; t[1][1] += eyv.y * mv.y; t[1][2] += eyv.y * mv.z; t[1][3] += eyv.y * mv.w;
        t[2][0] += eyv.z * mv.x; t[2][1] += eyv.z * mv.y; t[2][2] += eyv.z * mv.z; t[2][3] += eyv.z * mv.w;
        t[3][0] += eyv.w * mv.x; t[3][1] += eyv.w * mv.y; t[3][2] += eyv.w * mv.z; t[3][3] += eyv.w * mv.w;
      }
      float4 cv = *(float4*)&cinv[x0];
      #pragma unroll
      for (int i = 0; i < 4; ++i) {
        float4 exv = *(float4*)&ex[(n0 + i)*H + x0];
        sacc[i] += t[i][0]*exv.x*cv.x + t[i][1]*exv.y*cv.y
                 + t[i][2]*exv.z*cv.z + t[i][3]*exv.w*cv.w;
      }
    }
    // deterministic reduce across the 16 xt lanes of this n-group
    #pragma unroll
    for (int off = 8; off > 0; off >>= 1) {
      #pragma unroll
      for (int i = 0; i < 4; ++i) sacc[i] += __shfl_down(sacc[i], off, 16);
    }
    if (xt == 0) {
      #pragma unroll
      for (int i = 0; i < 4; ++i) ws_score[blk*NP + n0 + i] = sacc[i];
    }
  }
}

// Kernel 2: per-image normalize masks in place; block (b,c=0) reduces scores.
__global__ __launch_bounds__(256) void prs_finish(
    float* __restrict__ out,
    const float* __restrict__ ws_msum,
    const float* __restrict__ ws_score)
{
  __shared__ float invs;
  const int img = blockIdx.x;
  const int tid = threadIdx.x;
  if (tid == 0) {
    float s = 0.0f;
    for (int i = 0; i < G; ++i) s += ws_msum[img*G + i];
    invs = 1.0f / fmaxf(s, 1e-8f);
  }
  __syncthreads();
  const float inv = invs;
  float4* p = (float4*)(out + img*(H*H));
  for (int i = tid; i < (H*H)/4; i += 256) {
    float4 v = p[i];
    v.x *= inv; v.y *= inv; v.z *= inv; v.w *= inv;
    p[i] = v;
  }
  if ((img % 3) == 0 && tid < NP) {
    int b = img / 3;
    float s = 0.0f;
    for (int cc = 0; cc < 3; ++cc)
      for (int st = 0; st < G; ++st)
        s += ws_score[((b*3 + cc)*G + st)*NP + tid];
    out[NIMG*(H*H) + b*NP + tid] = s * (1.0f/3.0f);
  }
}

extern "C" void kernel_launch(void* const* d_in, const int* in_sizes, int n_in,
                              void* d_out, int out_size, void* d_ws, size_t ws_size,
                              hipStream_t stream) {
  const float* cam   = (const float*)d_in[0];
  const float* cloud = (const float*)d_in[1];
  const float* mt    = (const float*)d_in[2];
  const float* blur  = (const float*)d_in[3];
  const float* b3    = (const float*)d_in[4];
  const float* b2    = (const float*)d_in[5];
  float* out = (float*)d_out;

  float* ws_msum  = (float*)d_ws;          // 240 floats (pad to 256)
  float* ws_score = ws_msum + 256;         // 240*64 floats

  prs_main<<<NIMG * G, 256, 0, stream>>>(cam, cloud, mt, blur, b3, b2,
                                         out, ws_msum, ws_score);
  prs_finish<<<NIMG, 256, 0, stream>>>(out, ws_msum, ws_score);
}

// Round 2
// 20.229 us; speedup vs baseline: 1.4084x; 1.4084x over previous
//
#include <hip/hip_runtime.h>

#define H 200
#define NP 64
#define NIMG 24
#define NB 8            // batches
#define G 10            // y-strips per image
#define ROWS 20         // H / G
#define XH 2            // x-halves
#define XW 100          // H / XH
#define SPI (G*XH)      // strip-halves per image = 20
#define NBLK (NIMG*SPI) // 480
#define GSTEP (2.0f/199.0f)

// K1: one block per (img, y-strip of 20, x-half of 100).
// Waves 0-1: mask GEMM (ey^T @ ex, clamp, store, partial sum).
// Waves 2-3: score GEMM (T = ey @ M, fold with ex*cinv) -> ws_score.
__global__ __launch_bounds__(256) void prs_main(
    const float* __restrict__ cam,   // (8,3,2,3)
    const float* __restrict__ cloud, // (8,64,3)
    const float* __restrict__ mt,    // (8,3,200,200)
    const float* __restrict__ blur,  // (8,64)
    const float* __restrict__ b3,    // (8,3)
    const float* __restrict__ b2,    // (8,3,2)
    float* __restrict__ out,
    float* __restrict__ ws_msum,     // [NBLK]
    float* __restrict__ ws_score)    // [NBLK][64]
{
  __shared__ float ex[NP * XW];      // [n][xl]   25600 B
  __shared__ float eys[ROWS * NP];   // [y][n]     5120 B
  __shared__ float eyt[NP * ROWS];   // [n][y]     5120 B
  __shared__ float Syp[4 * NP];
  __shared__ float Sy[NP];
  __shared__ float cinv[XW];
  __shared__ float ptx[NP], pty[NP], i2s[NP];
  __shared__ float red[256];

  const int tid = threadIdx.x;
  const int blk = blockIdx.x;
  const int img = blk / SPI;
  const int rem = blk - img * SPI;
  const int strip = rem >> 1;
  const int xh = rem & 1;
  const int b = img / 3;
  const int c = img - b * 3;
  const int ys0 = strip * ROWS;
  const int xb = xh * XW;

  // --- point params ---
  if (tid < NP) {
    int n = tid;
    float p0 = cloud[(b*NP + n)*3 + 0] + b3[b*3 + 0];
    float p1 = cloud[(b*NP + n)*3 + 1] + b3[b*3 + 1];
    float p2 = cloud[(b*NP + n)*3 + 2] + b3[b*3 + 2];
    const float* cc = cam + ((b*3 + c)*2)*3;
    float px = cc[0]*p0 + cc[1]*p1 + cc[2]*p2 - b2[(b*3 + c)*2 + 0];
    float py = cc[3]*p0 + cc[4]*p1 + cc[5]*p2 - b2[(b*3 + c)*2 + 1];
    ptx[n] = fminf(fmaxf(px * 0.01f, -1.0f), 1.0f);
    pty[n] = fminf(fmaxf(py * 0.01f, -1.0f), 1.0f);
    float s = blur[b*NP + n];
    i2s[n] = 1.0f / (2.0f * s * s);
  }
  __syncthreads();

  // --- ex table for our x-half: 64 n x 100 xl ---
  {
    int n   = tid >> 2;
    int xl0 = (tid & 3) * 25;
    float pxv = ptx[n], iv = i2s[n];
    for (int k = 0; k < 25; ++k) {
      int xl = xl0 + k;
      float dx = (-1.0f + (xb + xl) * GSTEP) - pxv;
      ex[n*XW + xl] = __expf(-dx*dx*iv);
    }
  }
  // --- Sy partials (full y) + strip ey in both layouts ---
  {
    int n = tid & 63;
    int g = tid >> 6;
    float pyv = pty[n], iv = i2s[n];
    float s = 0.0f;
    for (int y = g*50; y < g*50 + 50; ++y) {
      float dy = (-1.0f + y * GSTEP) - pyv;
      s += __expf(-dy*dy*iv);
    }
    Syp[g*NP + n] = s;
    for (int k = 0; k < 5; ++k) {
      int y = g*5 + k;
      float dy = (-1.0f + (ys0 + y) * GSTEP) - pyv;
      float e = __expf(-dy*dy*iv);
      eys[y*NP + n] = e;
      eyt[n*ROWS + y] = e;
    }
  }
  __syncthreads();
  if (tid < NP) Sy[tid] = Syp[tid] + Syp[NP + tid] + Syp[2*NP + tid] + Syp[3*NP + tid];
  __syncthreads();
  if (tid < XW) {
    float s = 0.0f;
    for (int n = 0; n < NP; ++n) s += ex[n*XW + tid] * Sy[n];
    cinv[tid] = 1.0f / fmaxf(s, 1e-8f);
  }
  __syncthreads();

  float msl = 0.0f;
  if (tid < 128) {
    // ---- mask GEMM: 125 active threads, 4y x 4x register tiles over 20x100 ----
    if (tid < 125) {
      int yg = tid / 25;
      int xg = tid - yg * 25;
      int x0 = xg * 4, y0 = yg * 4;
      float acc[4][4];
      #pragma unroll
      for (int i = 0; i < 4; ++i)
        #pragma unroll
        for (int j = 0; j < 4; ++j) acc[i][j] = 0.0f;
      for (int n = 0; n < NP; ++n) {
        float4 exv = *(float4*)&ex[n*XW + x0];
        float4 eyv = *(float4*)&eyt[n*ROWS + y0];
        acc[0][0] += eyv.x*exv.x; acc[0][1] += eyv.x*exv.y; acc[0][2] += eyv.x*exv.z; acc[0][3] += eyv.x*exv.w;
        acc[1][0] += eyv.y*exv.x; acc[1][1] += eyv.y*exv.y; acc[1][2] += eyv.y*exv.z; acc[1][3] += eyv.y*exv.w;
        acc[2][0] += eyv.z*exv.x; acc[2][1] += eyv.z*exv.y; acc[2][2] += eyv.z*exv.z; acc[2][3] += eyv.z*exv.w;
        acc[3][0] += eyv.w*exv.x; acc[3][1] += eyv.w*exv.y; acc[3][2] += eyv.w*exv.z; acc[3][3] += eyv.w*exv.w;
      }
      #pragma unroll
      for (int i = 0; i < 4; ++i) {
        float4 v;
        v.x = fminf(acc[i][0], 1.0f);
        v.y = fminf(acc[i][1], 1.0f);
        v.z = fminf(acc[i][2], 1.0f);
        v.w = fminf(acc[i][3], 1.0f);
        msl += v.x + v.y + v.z + v.w;
        *(float4*)&out[img*(H*H) + (ys0 + y0 + i)*H + xb + x0] = v;
      }
    }
  } else {
    // ---- score GEMM: 128 threads = 16 n-groups x 8 x-lanes ----
    int st = tid - 128;
    int ng = st >> 3;
    int xt = st & 7;
    int n0 = ng * 4;
    float sacc[4] = {0.0f, 0.0f, 0.0f, 0.0f};
    for (int xq = xt; xq < 25; xq += 8) {
      int xl0 = xq * 4;
      float t[4][4];
      #pragma unroll
      for (int i = 0; i < 4; ++i)
        #pragma unroll
        for (int j = 0; j < 4; ++j) t[i][j] = 0.0f;
      for (int y = 0; y < ROWS; ++y) {
        float4 eyv = *(float4*)&eys[y*NP + n0];
        float4 mv  = *(const float4*)&mt[img*(H*H) + (ys0 + y)*H + xb + xl0];
        t[0][0] += eyv.x*mv.x; t[0][1] += eyv.x*mv.y; t[0][2] += eyv.x*mv.z; t[0][3] += eyv.x*mv.w;
        t[1][0] += eyv.y*mv.x; t[1][1] += eyv.y*mv.y; t[1][2] += eyv.y*mv.z; t[1][3] += eyv.y*mv.w;
        t[2][0] += eyv.z*mv.x; t[2][1] += eyv.z*mv.y; t[2][2] += eyv.z*mv.z; t[2][3] += eyv.z*mv.w;
        t[3][0] += eyv.w*mv.x; t[3][1] += eyv.w*mv.y; t[3][2] += eyv.w*mv.z; t[3][3] += eyv.w*mv.w;
      }
      float4 cv = *(float4*)&cinv[xl0];
      #pragma unroll
      for (int i = 0; i < 4; ++i) {
        float4 exv = *(float4*)&ex[(n0 + i)*XW + xl0];
        sacc[i] += t[i][0]*exv.x*cv.x + t[i][1]*exv.y*cv.y
                 + t[i][2]*exv.z*cv.z + t[i][3]*exv.w*cv.w;
      }
    }
    #pragma unroll
    for (int off = 4; off > 0; off >>= 1) {
      #pragma unroll
      for (int i = 0; i < 4; ++i) sacc[i] += __shfl_down(sacc[i], off, 8);
    }
    if (xt == 0) {
      #pragma unroll
      for (int i = 0; i < 4; ++i) ws_score[blk*NP + n0 + i] = sacc[i];
    }
  }

  red[tid] = msl;
  __syncthreads();
  #pragma unroll
  for (int s = 128; s > 0; s >>= 1) {
    if (tid < s) red[tid] += red[tid + s];
    __syncthreads();
  }
  if (tid == 0) ws_msum[blk] = red[0];
}

// K2: blocks 0..479 normalize one 20x100 mask region; blocks 480..487 reduce scores.
__global__ __launch_bounds__(256) void prs_finish(
    float* __restrict__ out,
    const float* __restrict__ ws_msum,
    const float* __restrict__ ws_score)
{
  const int blk = blockIdx.x;
  const int tid = threadIdx.x;
  if (blk < NBLK) {
    const int img = blk / SPI;
    const int rem = blk - img * SPI;
    const int strip = rem >> 1;
    const int xh = rem & 1;
    __shared__ float invs;
    if (tid == 0) {
      float s = 0.0f;
      for (int i = 0; i < SPI; ++i) s += ws_msum[img*SPI + i];
      invs = 1.0f / fmaxf(s, 1e-8f);
    }
    __syncthreads();
    const float inv = invs;
    for (int q = tid; q < 500; q += 256) {   // 20 rows x 25 float4
      int ry = q / 25;
      int rx = q - ry * 25;
      float* p = out + img*(H*H) + (strip*ROWS + ry)*H + xh*XW + rx*4;
      float4 v = *(float4*)p;
      v.x *= inv; v.y *= inv; v.z *= inv; v.w *= inv;
      *(float4*)p = v;
    }
  } else {
    const int bb = blk - NBLK;
    if (tid < NP) {
      float s = 0.0f;
      for (int cc = 0; cc < 3; ++cc)
        for (int sh = 0; sh < SPI; ++sh)
          s += ws_score[(((bb*3 + cc)*SPI) + sh)*NP + tid];
      out[NIMG*(H*H) + bb*NP + tid] = s * (1.0f/3.0f);
    }
  }
}

extern "C" void kernel_launch(void* const* d_in, const int* in_sizes, int n_in,
                              void* d_out, int out_size, void* d_ws, size_t ws_size,
                              hipStream_t stream) {
  const float* cam   = (const float*)d_in[0];
  const float* cloud = (const float*)d_in[1];
  const float* mt    = (const float*)d_in[2];
  const float* blur  = (const float*)d_in[3];
  const float* b3    = (const float*)d_in[4];
  const float* b2    = (const float*)d_in[5];
  float* out = (float*)d_out;

  float* ws_msum  = (float*)d_ws;          // 480 floats (pad to 512)
  float* ws_score = ws_msum + 512;         // 480*64 floats

  prs_main<<<NBLK, 256, 0, stream>>>(cam, cloud, mt, blur, b3, b2,
                                     out, ws_msum, ws_score);
  prs_finish<<<NBLK + NB, 256, 0, stream>>>(out, ws_msum, ws_score);
}